// Round 8
// baseline (180.358 us; speedup 1.0000x reference)
//
#include <hip/hip_runtime.h>

#define EPS 1e-8f

typedef float f32x4 __attribute__((ext_vector_type(4)));

// ---------------------------------------------------------------------------
// Output layout (floats):
//   [0,        65536)      concrete_lower  [64,1024]
//   [65536,    131072)     concrete_upper  [64,1024]
//   [131072,   67239936)   lower_coef      [64,1024,1024] (diag only)
//   [67239936, 134348800)  upper_coef      [64,1024,1024] (diag only)
//   [134348800,134414336)  lower_bias      [64,1024] (zeros)
//   [134414336,134479872)  upper_bias      [64,1024] (mu_upper)
//
// Single fused dispatch, 256 blocks (1/CU). Virtual rows of 1024 floats:
//   vr in [0, 131072)       coef rows (diag col = vr & 1023)
//   vr in [131072, 131136)  lower_bias rows (zeros)
//   vr in [131136, 131200)  concrete_lower rows
//   vr in [131200, 131264)  concrete_upper rows
//   vr in [131264, 131328)  upper_bias rows (mu)
// 131328 = 256 * 513 exactly. Block b owns rows [513b, 513b+513) -- a
// contiguous ~2.1 MB region walked front-to-back, 4 KB per iteration
// (256 threads x f32x4), so the chip sees only 256 sequential write
// streams (R5 evidence: fewer streams -> higher DRAM efficiency).
// PLAIN stores, not nontemporal: rocclr's fillBufferAligned uses cached
// stores and sustains 6.55 TB/s; nt peaked at 5.3 TB/s (R4/R5 evidence).
// All branches are block-uniform (row-level), so no lane divergence.
// ---------------------------------------------------------------------------

__global__ void __launch_bounds__(256, 1)
fused_fill_kernel(const float* __restrict__ lower,
                  const float* __restrict__ upper,
                  float* __restrict__ out) {
    const int tid = threadIdx.x;
    const long long vr0 = (long long)blockIdx.x * 513;

    // ---- coef rows (all 513 for blocks 0..254; first 257 for block 255) ----
    int ncoef = (int)(131072 - vr0);
    if (ncoef > 513) ncoef = 513;
    float* dst = out + 131072 + vr0 * 1024 + tid * 4;
#pragma unroll 4
    for (int ri = 0; ri < ncoef; ++ri) {
        const int vr = (int)vr0 + ri;
        const int rr = vr & 65535;            // flat (b,i) into [64,1024]
        const float l = lower[rr];            // block-uniform scalar load
        const float u = upper[rr];
        const bool active = (l >= 0.0f);
        const bool crossing = (l < 0.0f) && (u > 0.0f);
        const float lam = crossing ? u / (u - l + EPS) : 0.0f;
        const float v = active ? 1.0f : (vr < 65536 ? 0.0f : lam);
        const int i = vr & 1023;              // diagonal column
        f32x4 z = {0.0f, 0.0f, 0.0f, 0.0f};
        if ((i >> 2) == tid) z[i & 3] = v;    // thread tid owns cols 4t..4t+3
        *(f32x4*)dst = z;
        dst += 1024;
    }

    // ---- small-output rows (block 255 only: ri 257..512) ----
    for (int ri = ncoef; ri < 513; ++ri) {
        const int vr = (int)vr0 + ri;
        if (vr < 131136) {
            // lower_bias row: zeros
            const int r = vr - 131072;
            const f32x4 z = {0.0f, 0.0f, 0.0f, 0.0f};
            *((f32x4*)(out + 134348800LL + (long long)r * 1024) + tid) = z;
        } else if (vr < 131200) {
            // concrete_lower row
            const int r = vr - 131136;
            f32x4 a = *((const f32x4*)(lower + (size_t)r * 1024) + tid);
            a.x = fmaxf(a.x, 0.0f);
            a.y = fmaxf(a.y, 0.0f);
            a.z = fmaxf(a.z, 0.0f);
            a.w = fmaxf(a.w, 0.0f);
            *((f32x4*)(out + (size_t)r * 1024) + tid) = a;
        } else if (vr < 131264) {
            // concrete_upper row
            const int r = vr - 131200;
            f32x4 a = *((const f32x4*)(upper + (size_t)r * 1024) + tid);
            a.x = fmaxf(a.x, 0.0f);
            a.y = fmaxf(a.y, 0.0f);
            a.z = fmaxf(a.z, 0.0f);
            a.w = fmaxf(a.w, 0.0f);
            *((f32x4*)(out + 65536 + (size_t)r * 1024) + tid) = a;
        } else {
            // upper_bias row: mu
            const int r = vr - 131264;
            f32x4 lv = *((const f32x4*)(lower + (size_t)r * 1024) + tid);
            f32x4 uv = *((const f32x4*)(upper + (size_t)r * 1024) + tid);
            f32x4 m;
#pragma unroll
            for (int e = 0; e < 4; ++e) {
                float l = lv[e], u = uv[e];
                bool crossing = (l < 0.0f) && (u > 0.0f);
                float lam = crossing ? u / (u - l + EPS) : 0.0f;
                m[e] = crossing ? -lam * l : 0.0f;
            }
            *((f32x4*)(out + 134414336LL + (size_t)r * 1024) + tid) = m;
        }
    }
}

extern "C" void kernel_launch(void* const* d_in, const int* in_sizes, int n_in,
                              void* d_out, int out_size, void* d_ws, size_t ws_size,
                              hipStream_t stream) {
    const float* lower = (const float*)d_in[0];
    const float* upper = (const float*)d_in[1];
    float* out = (float*)d_out;

    // One dispatch writes every output byte exactly once.
    fused_fill_kernel<<<256, 256, 0, stream>>>(lower, upper, out);
}

// Round 9
// 110.624 us; speedup vs baseline: 1.6304x; 1.6304x over previous
//
#include <hip/hip_runtime.h>

#define EPS 1e-8f

typedef float f32x4 __attribute__((ext_vector_type(4)));

// ---------------------------------------------------------------------------
// Output layout (floats):
//   [0,        65536)      concrete_lower  [64,1024]
//   [65536,    131072)     concrete_upper  [64,1024]
//   [131072,   67239936)   lower_coef      [64,1024,1024] (diag only)
//   [67239936, 134348800)  upper_coef      [64,1024,1024] (diag only)
//   [134348800,134414336)  lower_bias      [64,1024] (zeros)
//   [134414336,134479872)  upper_bias      [64,1024] (mu_upper)
//
// R9: replicate the rocclr fillBufferAligned configuration exactly —
// PLAIN (cached) dwordx4 stores + GRID-STRIDE interleave + low occupancy
// (256 blocks x 256 threads = 1024 waves ~= rocclr's ~850-wave / 10%
// occupancy regime). Grid-stride keeps the instantaneous store window a
// single dense ~1 MB sliding band (good DRAM row locality); plain stores
// let L2 aggregate full lines and burst dirty evictions (rocclr evidence:
// 6.55-6.8 TB/s every round). No value loads inside the fill loop (R8
// lesson: a dependent uniform load per row serializes the stream).
// Zero region: floats [131072, 134414336) = 33570816 f32x4
//            = 65536 threads * 512 + 16384.
// ---------------------------------------------------------------------------

__global__ void __launch_bounds__(256)
fill_zero_kernel(f32x4* __restrict__ dst) {
    const int g = blockIdx.x * 256 + threadIdx.x;   // 0..65535
#pragma unroll 4
    for (int i = 0; i < 512; ++i) {
        const f32x4 z = {0.0f, 0.0f, 0.0f, 0.0f};
        dst[(size_t)i * 65536 + g] = z;
    }
    if (g < 16384) {
        const f32x4 z = {0.0f, 0.0f, 0.0f, 0.0f};
        dst[(size_t)512 * 65536 + g] = z;
    }
}

__global__ void diag_small_kernel(const float* __restrict__ lower,
                                  const float* __restrict__ upper,
                                  float* __restrict__ out) {
    const int BN = 65536;  // 64*1024
    int t = blockIdx.x * blockDim.x + threadIdx.x;
    if (t >= 2 * BN) return;
    int rr = t & (BN - 1);       // flat (b, i) index into [64,1024]
    int i  = rr & 1023;          // neuron index => diagonal column
    float l = lower[rr];
    float u = upper[rr];
    bool active   = (l >= 0.0f);
    bool crossing = (l < 0.0f) && (u > 0.0f);
    float lam = crossing ? u / (u - l + EPS) : 0.0f;

    // Diagonal element of lower_coef (t < BN) or upper_coef (t >= BN).
    float v = active ? 1.0f : (t < BN ? 0.0f : lam);
    if (v != 0.0f) {
        out[131072LL + (long long)t * 1024 + i] = v;
    }

    if (t < BN) {
        float mu = crossing ? -lam * l : 0.0f;
        out[t]                  = fmaxf(l, 0.0f);   // concrete_lower
        out[BN + t]             = fmaxf(u, 0.0f);   // concrete_upper
        out[134414336LL + t]    = mu;               // upper_bias
        // lower_bias zeros covered by fill_zero_kernel.
    }
}

extern "C" void kernel_launch(void* const* d_in, const int* in_sizes, int n_in,
                              void* d_out, int out_size, void* d_ws, size_t ws_size,
                              hipStream_t stream) {
    const float* lower = (const float*)d_in[0];
    const float* upper = (const float*)d_in[1];
    float* out = (float*)d_out;

    // Zero both coef tensors + lower_bias: floats [131072, 134414336).
    fill_zero_kernel<<<256, 256, 0, stream>>>((f32x4*)(out + 131072));

    // Scatter diagonals + small outputs (after fill on same stream).
    diag_small_kernel<<<512, 256, 0, stream>>>(lower, upper, out);
}